// Round 7
// baseline (1066.957 us; speedup 1.0000x reference)
//
#include <hip/hip_runtime.h>

#define T_ 64

typedef __attribute__((ext_vector_type(4))) float f32x4;
typedef __attribute__((ext_vector_type(8))) short s16x8;

__device__ __forceinline__ unsigned short f2bf(float f) {
  unsigned u = __float_as_uint(f);
  u = (u + 0x7FFFu + ((u >> 16) & 1u)) >> 16;
  return (unsigned short)u;
}
__device__ __forceinline__ float bf2f(unsigned short h) {
  return __uint_as_float(((unsigned)h) << 16);
}
__device__ __forceinline__ float eluf(float x) { return x > 0.f ? x : __expf(x) - 1.f; }
__device__ __forceinline__ float sigmf(float x) { return 1.f / (1.f + __expf(-x)); }
__device__ __forceinline__ float tanh_(float x) {
  float xx = fminf(fmaxf(x, -30.f), 30.f);
  float e = __expf(-2.f * xx);
  return (1.f - e) / (1.f + e);
}
__device__ __forceinline__ float softpf(float x) {
  return x > 20.f ? x : __logf(1.f + __expf(x));
}

// ---- pk layout (u16 offsets) ----
#define OPW1   0        // img1 kt0 only: 13*512 = 6656
#define OPWI   6656     // wi per-gate [3][13][6]: 119808
#define OPWH   126464   // wh per-gate [3][13][6]: 119808
#define OPO1D  246272   // obs1d [13][6]: 39936
#define OPO2   286208   // obs2 [4][6]: 12288
#define OPI2   298496   // img2 KT7 NT13: 46592 (post_head)
#define OPI3   345088   // img3 KT7 NT4: 14336 (post_head)
#define OWIWT  359424   // wi k=192..199 [3][208][8]: 4992
#define OWHWT  364416   // wh k-rem [3][208][8]: 4992
#define OO1DWT 369408   // [208][8]: 1664
#define OI1WT  371072   // img1 k=32..39 [208][8]: 1664
#define OO2WT  372736   // [64][8]: 512
#define PK_U16 373248

#define OFF_PK  26214400
#define OFF_SWZ 26960896

__device__ void pack_mat(int idx, int stride, const float* __restrict__ W,
                         int K, int N, int KT, int NT, unsigned short* __restrict__ dst) {
  int total = KT * NT * 512;
  for (int i = idx; i < total; i += stride) {
    int j = i & 7, l = (i >> 3) & 63, rem = i >> 9;
    int kt = rem % KT, nt = rem / KT;
    int n = nt * 16 + (l & 15), k = kt * 32 + (l >> 4) * 8 + j;
    float v = (k < K && n < N) ? W[(size_t)k * N + n] : 0.f;
    dst[i] = f2bf(v);
  }
}

__device__ void pack_gate(int idx, int stride, const float* __restrict__ W,
                          unsigned short* __restrict__ dst) {
  int total = 3 * 13 * 6 * 512;
  for (int i = idx; i < total; i += stride) {
    int j = i & 7, l = (i >> 3) & 63, rem = i >> 9;
    int kt = rem % 6, rem2 = rem / 6, nt = rem2 % 13, g = rem2 / 13;
    int u = nt * 16 + (l & 15);
    int k = kt * 32 + (l >> 4) * 8 + j;
    float v = (u < 200) ? W[(size_t)k * 600 + g * 200 + u] : 0.f;
    dst[i] = f2bf(v);
  }
}

__global__ void prep_weights(const float* __restrict__ w1, const float* __restrict__ wi,
                             const float* __restrict__ wh, const float* __restrict__ i2,
                             const float* __restrict__ i3, const float* __restrict__ obs1w,
                             const float* __restrict__ o2,
                             unsigned short* __restrict__ pk,
                             unsigned short* __restrict__ swz) {
  int idx = blockIdx.x * blockDim.x + threadIdx.x;
  int stride = gridDim.x * blockDim.x;
  pack_mat(idx, stride, w1, 40, 200, 1, 13, pk + OPW1);
  pack_gate(idx, stride, wi, pk + OPWI);
  pack_gate(idx, stride, wh, pk + OPWH);
  pack_mat(idx, stride, obs1w, 200, 200, 6, 13, pk + OPO1D);
  pack_mat(idx, stride, o2, 200, 60, 6, 4, pk + OPO2);
  pack_mat(idx, stride, i2, 200, 200, 7, 13, pk + OPI2);
  pack_mat(idx, stride, i3, 200, 60, 7, 4, pk + OPI3);
  for (int i = idx; i < 4992; i += stride) {
    int j = i & 7, c = (i >> 3) % 208, g = i / 1664;
    pk[OWIWT + i] = f2bf((c < 200) ? wi[(size_t)(192 + j) * 600 + g * 200 + c] : 0.f);
    pk[OWHWT + i] = f2bf((c < 200) ? wh[(size_t)(192 + j) * 600 + g * 200 + c] : 0.f);
  }
  for (int i = idx; i < 1664; i += stride) {
    int c = i >> 3, j = i & 7;
    pk[OO1DWT + i] = f2bf((c < 200) ? obs1w[(size_t)(192 + j) * 200 + c] : 0.f);
    pk[OI1WT + i]  = f2bf((c < 200) ? w1[(size_t)(32 + j) * 200 + c] : 0.f);
  }
  for (int i = idx; i < 512; i += stride) {
    int c = i >> 3, j = i & 7;
    pk[OO2WT + i] = f2bf((c < 60) ? o2[(size_t)(192 + j) * 60 + c] : 0.f);
  }
  for (int i = idx; i < 212992; i += stride) {
    int j = i & 7, l = (i >> 3) & 63, rem = i >> 9;
    int nt = rem % 13, kc = rem / 13;
    int k = kc * 32 + ((l >> 4) * 8) + j;
    int n = nt * 16 + (l & 15);
    float v = (n < 200) ? obs1w[(size_t)(200 + k) * 200 + n] : 0.0f;
    swz[i] = f2bf(v);
  }
}

// --------------------------------------------------------------------------
// emb_pre = embed @ obs1_w[200:,:] + obs1_b   (validated)
// --------------------------------------------------------------------------
__global__ __launch_bounds__(256) void emb_gemm(const float* __restrict__ embed,
                                                const float* __restrict__ obs1b,
                                                const unsigned short* __restrict__ swz,
                                                unsigned short* __restrict__ emb_pre) {
  __shared__ __align__(16) unsigned short lds_A[64][40];
  int tid = threadIdx.x;
  int lane = tid & 63, w = tid >> 6;
  int R0 = blockIdx.x * 64;
  int tt = R0 >> 10;
  int bb = R0 & 1023;

  f32x4 acc[13];
#pragma unroll
  for (int nt = 0; nt < 13; ++nt) acc[nt] = (f32x4){0.f, 0.f, 0.f, 0.f};

  int i_row = tid >> 2, cg = tid & 3;
  const float* arow = embed + ((size_t)(bb + i_row) * 64 + tt) * 1024 + cg * 8;

  for (int kc = 0; kc < 32; ++kc) {
    __syncthreads();
    {
      const float* p = arow + kc * 32;
      f32x4 a0 = *(const f32x4*)p;
      f32x4 a1 = *(const f32x4*)(p + 4);
      unsigned short* dst = &lds_A[i_row][cg * 8];
      dst[0] = f2bf(a0[0]); dst[1] = f2bf(a0[1]); dst[2] = f2bf(a0[2]); dst[3] = f2bf(a0[3]);
      dst[4] = f2bf(a1[0]); dst[5] = f2bf(a1[1]); dst[6] = f2bf(a1[2]); dst[7] = f2bf(a1[3]);
    }
    __syncthreads();
    s16x8 af = *(const s16x8*)&lds_A[w * 16 + (lane & 15)][(lane >> 4) * 8];
    const unsigned short* bp = swz + (size_t)kc * 6656 + (size_t)lane * 8;
#pragma unroll
    for (int nt = 0; nt < 13; ++nt) {
      s16x8 bfv = *(const s16x8*)(bp + nt * 512);
      acc[nt] = __builtin_amdgcn_mfma_f32_16x16x32_bf16(af, bfv, acc[nt], 0, 0, 0);
    }
  }
  int r0 = R0 + w * 16 + ((lane >> 4) << 2);
  int c0 = lane & 15;
#pragma unroll
  for (int nt = 0; nt < 13; ++nt) {
    int n = nt * 16 + c0;
    if (n < 200) {
      float bv = obs1b[n];
#pragma unroll
      for (int rr = 0; rr < 4; ++rr)
        emb_pre[(size_t)(r0 + rr) * 200 + n] = f2bf(acc[nt][rr] + bv);
    }
  }
}

// --------------------------------------------------------------------------
// scan_v7: 64 blocks x 512 thr (8 waves, 2/SIMD). Balanced 48-tile/wave
// static-slot stream; wh(+extras) resident; obs head on waves 5-7.
// --------------------------------------------------------------------------
#define LGKM0  asm volatile("s_waitcnt lgkmcnt(0)" ::: "memory")
#define MEMCLB asm volatile("" ::: "memory")
#define BAR()  __builtin_amdgcn_s_barrier()
#define MFMA16(A, B, C) __builtin_amdgcn_mfma_f32_16x16x32_bf16((A), (B), (C), 0, 0, 0)
#define WV9  asm volatile("s_waitcnt vmcnt(9)" ::: "memory")
#define WV29 asm volatile("s_waitcnt vmcnt(29)" ::: "memory")
#define WV4  asm volatile("s_waitcnt vmcnt(4)" ::: "memory")
#define WV0  asm volatile("s_waitcnt vmcnt(0)" ::: "memory")

typedef __attribute__((address_space(3))) unsigned int u32_lds;
typedef const __attribute__((address_space(1))) unsigned int u32_glb;

__device__ __forceinline__ void gll16(const unsigned short* g, unsigned short* l, int lane) {
  __builtin_amdgcn_global_load_lds((u32_glb*)(g + lane * 8), (u32_lds*)l, 16, 0, 0);
}

// consume 6 streamed tiles at absolute taus TB..TB+5 into acc (A-frags A[0..5])
template <int TB, bool BIGB>
__device__ __forceinline__ f32x4 cons6(const s16x8* A, f32x4 acc,
                                       unsigned short* ringw, const unsigned* toffw,
                                       const unsigned short* pk, int lane) {
#pragma unroll
  for (int kt = 0; kt < 6; ++kt) {
    const int tau = TB + kt;
    if ((tau & 3) == 0) {
      if (tau < 8) { if (BIGB) { WV29; } else { WV9; } }
      else { WV4; }
    }
    s16x8 Bv = *(const s16x8*)(ringw + (tau & 7) * 512 + lane * 8);
    acc = MFMA16(A[kt], Bv, acc);
    if ((tau & 3) == 3) {
      LGKM0; MEMCLB;
#pragma unroll
      for (int k2 = 1; k2 <= 4; ++k2) {
        const int tile = (tau + 4 + k2) % 48;
        gll16(pk + toffw[tile], ringw + (tile & 7) * 512, lane);
      }
      MEMCLB;
    }
  }
  return acc;
}

__device__ __forceinline__ f32x4 res6(const s16x8* A, const s16x8* Wt, f32x4 acc) {
#pragma unroll
  for (int kt = 0; kt < 6; ++kt) acc = MFMA16(A[kt], Wt[kt], acc);
  return acc;
}
__device__ __forceinline__ f32x4 rem1(const s16x8& A6, const unsigned short* wt,
                                      const unsigned short* zb, bool kg0, f32x4 acc) {
  const unsigned short* p = kg0 ? wt : zb;
  return MFMA16(A6, *(const s16x8*)p, acc);
}
__device__ __forceinline__ void grustep(const f32x4& rv, const f32x4& zv,
                                        const f32x4& inv, const f32x4& hnv, f32x4& dv) {
#pragma unroll
  for (int rr = 0; rr < 4; ++rr) {
    float r = sigmf(rv[rr]);
    float z = sigmf(zv[rr]);
    float n = tanh_(inv[rr] + r * hnv[rr]);
    dv[rr] = (1.f - z) * n + z * dv[rr];
  }
}

__global__ __launch_bounds__(512, 1) void scan_v7(
    const float* __restrict__ action, const float* __restrict__ eps_post,
    const float* __restrict__ img1_b, const float* __restrict__ gru_bi,
    const float* __restrict__ gru_bh, const float* __restrict__ obs2_b,
    const unsigned short* __restrict__ pk, const unsigned short* __restrict__ emb_pre,
    float* __restrict__ out) {

  __shared__ __align__(16) unsigned short ring[8][8][512];  // 64 KB
  __shared__ __align__(16) unsigned short l_w1[13 * 512];
  __shared__ __align__(16) unsigned short l_wiWT[3][208][8];
  __shared__ __align__(16) unsigned short l_whWT[3][208][8];
  __shared__ __align__(16) unsigned short l_o1dWT[208][8];
  __shared__ __align__(16) unsigned short l_i1WT[208][8];
  __shared__ __align__(16) unsigned short l_o2WT[64][8];
  __shared__ __align__(16) unsigned short zblk[8];
  __shared__ __align__(16) unsigned short xoA[28][16][8];
  __shared__ __align__(16) unsigned short dA[28][16][8];
  __shared__ __align__(16) unsigned short sA[8][16][8];
  __shared__ __align__(16) float s_o[60][20];
  __shared__ __align__(16) float outbuf[16][292];
  __shared__ unsigned l_toff[8][48];

  const int tid = threadIdx.x, lane = tid & 63, w = tid >> 6;
  const int arow = lane & 15, kg = lane >> 4;
  const bool kg0 = (kg == 0);
  const int b0 = blockIdx.x * 16;
  unsigned short* ringw = &ring[w][0][0];
  const unsigned* toffw = &l_toff[w][0];

  // ---------- prologue: LDS tables ----------
  for (int i = tid; i < 28 * 16 * 8; i += 512) { (&xoA[0][0][0])[i] = 0; (&dA[0][0][0])[i] = 0; }
  for (int i = tid; i < 8 * 16 * 8; i += 512) (&sA[0][0][0])[i] = 0;
  for (int i = tid; i < 13 * 512; i += 512) l_w1[i] = pk[OPW1 + i];
  for (int i = tid; i < 4992; i += 512) {
    (&l_wiWT[0][0][0])[i] = pk[OWIWT + i];
    (&l_whWT[0][0][0])[i] = pk[OWHWT + i];
  }
  for (int i = tid; i < 1664; i += 512) {
    (&l_o1dWT[0][0])[i] = pk[OO1DWT + i];
    (&l_i1WT[0][0])[i] = pk[OI1WT + i];
  }
  for (int i = tid; i < 512; i += 512) (&l_o2WT[0][0])[i] = pk[OO2WT + i];
  if (tid < 8) zblk[tid] = 0;
  // stream tile-offset tables
  for (int i = tid; i < 8 * 48; i += 512) {
    int ww = i / 48, tau = i % 48;
    unsigned off;
    if (ww < 5) {
      if (tau < 18) { int g = tau / 6, kt = tau % 6; off = OPWI + ((g * 13 + ww) * 6 + kt) * 512; }
      else {
        int t2 = tau - 18, ug = ww + 8;
        if (t2 < 6)       off = OPWI + ((0 * 13 + ug) * 6 + t2) * 512;
        else if (t2 < 12) off = OPWI + ((1 * 13 + ug) * 6 + (t2 - 6)) * 512;
        else if (t2 < 18) off = OPWH + ((1 * 13 + ug) * 6 + (t2 - 12)) * 512;
        else if (t2 < 24) off = OPWI + ((2 * 13 + ug) * 6 + (t2 - 18)) * 512;
        else              off = OPWH + ((2 * 13 + ug) * 6 + (t2 - 24)) * 512;
      }
    } else {
      if (tau < 18) { int g = tau / 6, kt = tau % 6; off = OPWI + ((g * 13 + ww) * 6 + kt) * 512; }
      else if (tau < 42) {
        int i4 = (tau - 18) / 6, kt = (tau - 18) % 6;
        int nt = (ww - 5) * 4 + i4;
        off = OPO1D + (nt * 6 + kt) * 512;
      } else {
        int kt = tau - 42;
        int nt5 = (ww == 5) ? 0 : (ww == 6) ? 1 : 3;
        off = OPO2 + (nt5 * 6 + kt) * 512;
      }
    }
    l_toff[ww][tau] = off;
  }

  // ---------- resident weights (24 tiles, 96 VGPR) ----------
  s16x8 wB[4][6];
  {
    const unsigned short* base[4];
    if (w < 5) {
      base[0] = pk + OPWH + (size_t)((0 * 13 + w) * 6) * 512;
      base[1] = pk + OPWH + (size_t)((1 * 13 + w) * 6) * 512;
      base[2] = pk + OPWH + (size_t)((2 * 13 + w) * 6) * 512;
      base[3] = pk + OPWH + (size_t)((0 * 13 + w + 8) * 6) * 512;   // wh-r of ug_b
    } else {
      base[0] = pk + OPWH + (size_t)((0 * 13 + w) * 6) * 512;
      base[1] = pk + OPWH + (size_t)((1 * 13 + w) * 6) * 512;
      base[2] = pk + OPWH + (size_t)((2 * 13 + w) * 6) * 512;
      if (w == 5)      base[3] = pk + OPO1D + (size_t)(12 * 6) * 512;  // o1d nt12
      else if (w == 7) base[3] = pk + OPO2 + (size_t)(2 * 6) * 512;    // o2 nt2
      else             base[3] = pk + OPO1D;                            // unused
    }
#pragma unroll
    for (int s = 0; s < 4; ++s)
#pragma unroll
      for (int kt = 0; kt < 6; ++kt)
        wB[s][kt] = *(const s16x8*)(base[s] + (size_t)kt * 512 + lane * 8);
  }

  // ---------- biases ----------
  const int uA = w * 16 + arow;               // w<5: ug_a (<80); w>=5: ug (<128)
  const int uB = (w + 8) * 16 + arow;         // ug_b for w<5 (128..207)
  const bool mB = (w < 5) && (uB < 200);
  const int uBc = (uB < 200) ? uB : 199;
  float bsA0 = gru_bi[uA] + gru_bh[uA];
  float bsA1 = gru_bi[200 + uA] + gru_bh[200 + uA];
  float bi2a = gru_bi[400 + uA], bh2a = gru_bh[400 + uA];
  float bsB0 = mB ? (gru_bi[uBc] + gru_bh[uBc]) : 0.f;
  float bsB1 = mB ? (gru_bi[200 + uBc] + gru_bh[200 + uBc]) : 0.f;
  float bi2b = mB ? gru_bi[400 + uBc] : 0.f;
  float bh2b = mB ? gru_bh[400 + uBc] : 0.f;
  float b1A = img1_b[uA];
  float b1B = mB ? img1_b[uBc] : 0.f;
  float b5a = 0.f, b5b = 0.f;
  if (w == 5) b5a = obs2_b[arow];
  else if (w == 6) b5a = obs2_b[16 + arow];
  else if (w == 7) { b5a = (48 + arow < 60) ? obs2_b[48 + arow] : 0.f; b5b = obs2_b[32 + arow]; }

  // ---------- aux for t=0 ----------
  unsigned short e16[20];
#pragma unroll
  for (int i = 0; i < 20; ++i) e16[i] = 0;
  if (w >= 5) {
#pragma unroll
    for (int i = 0; i < 5; ++i) {
      int nt = (w == 5) ? ((i < 4) ? i : 12) : ((w == 6) ? (4 + ((i < 4) ? i : 3)) : (8 + ((i < 4) ? i : 3)));
      int c = nt * 16 + arow; int cc = (c < 200) ? c : 199;
#pragma unroll
      for (int rr = 0; rr < 4; ++rr)
        e16[i * 4 + rr] = emb_pre[((size_t)(b0 + kg * 4 + rr)) * 200 + cc];
    }
  }
  float epsv;
  { int it = (tid < 480) ? tid : 479;
    epsv = eps_post[((size_t)(b0 + it / 30)) * 30 + it % 30]; }
  float act0, actn;
  { int sl = (lane < 20) ? (w * 20 + lane) : (w * 20);
    act0 = action[((size_t)(b0 + sl / 10) * T_ + 0) * 10 + sl % 10];
    actn = action[((size_t)(b0 + sl / 10) * T_ + 1) * 10 + sl % 10]; }
  f32x4 dv0 = {0.f, 0.f, 0.f, 0.f}, dv1 = {0.f, 0.f, 0.f, 0.f};

  __syncthreads();
  if (lane < 20) {
    int sl = w * 20 + lane; int kk = sl % 10, r = sl / 10;
    sA[(30 + kk) >> 3][r][(30 + kk) & 7] = f2bf(act0);
  }
  // prologue ring: batches 0,1
#pragma unroll
  for (int tt = 0; tt < 8; ++tt) gll16(pk + toffw[tt], ringw + tt * 512, lane);
  WV0;
  __syncthreads();

  // ---------------- T loop ----------------
  for (int t = 0; t < T_; ++t) {
    // ===== S1 =====
    {
      s16x8 a0 = *(const s16x8*)&sA[kg][arow][0];
      s16x8 a1 = *(const s16x8*)&sA[4 + kg][arow][0];
      {
        s16x8 B0 = *(const s16x8*)&l_w1[w * 512 + lane * 8];
        f32x4 acc = {b1A, b1A, b1A, b1A};
        acc = MFMA16(a0, B0, acc);
        acc = rem1(a1, &l_i1WT[uA][0], zblk, kg0, acc);
#pragma unroll
        for (int rr = 0; rr < 4; ++rr)
          xoA[uA >> 3][kg * 4 + rr][uA & 7] = f2bf(eluf(acc[rr]));
      }
      if (w < 5) {
        s16x8 B0 = *(const s16x8*)&l_w1[(w + 8) * 512 + lane * 8];
        f32x4 acc = {b1B, b1B, b1B, b1B};
        acc = MFMA16(a0, B0, acc);
        acc = rem1(a1, &l_i1WT[uB][0], zblk, kg0, acc);
        if (uB < 200) {
#pragma unroll
          for (int rr = 0; rr < 4; ++rr)
            xoA[uB >> 3][kg * 4 + rr][uB & 7] = f2bf(eluf(acc[rr]));
        }
      }
    }
    LGKM0; BAR();   // B1: xA ready

    // ===== S2 + GRU =====
    {
      s16x8 ax[6], ad[6];
#pragma unroll
      for (int kt = 0; kt < 6; ++kt) {
        ax[kt] = *(const s16x8*)&xoA[kt * 4 + kg][arow][0];
        ad[kt] = *(const s16x8*)&dA[kt * 4 + kg][arow][0];
      }
      s16x8 ax6 = *(const s16x8*)&xoA[24 + kg][arow][0];
      s16x8 ad6 = *(const s16x8*)&dA[24 + kg][arow][0];
      if (w < 5) {
        // --- ug_a = w (taus 0..17, wh resident) ---
        f32x4 rv = cons6<0, false>(ax, (f32x4){bsA0, bsA0, bsA0, bsA0}, ringw, toffw, pk, lane);
        rv = rem1(ax6, &l_wiWT[0][uA][0], zblk, kg0, rv);
        rv = res6(ad, wB[0], rv);
        rv = rem1(ad6, &l_whWT[0][uA][0], zblk, kg0, rv);
        f32x4 zv = cons6<6, false>(ax, (f32x4){bsA1, bsA1, bsA1, bsA1}, ringw, toffw, pk, lane);
        zv = rem1(ax6, &l_wiWT[1][uA][0], zblk, kg0, zv);
        zv = res6(ad, wB[1], zv);
        zv = rem1(ad6, &l_whWT[1][uA][0], zblk, kg0, zv);
        f32x4 inv = cons6<12, false>(ax, (f32x4){bi2a, bi2a, bi2a, bi2a}, ringw, toffw, pk, lane);
        inv = rem1(ax6, &l_wiWT[2][uA][0], zblk, kg0, inv);
        f32x4 hnv = res6(ad, wB[2], (f32x4){bh2a, bh2a, bh2a, bh2a});
        hnv = rem1(ad6, &l_whWT[2][uA][0], zblk, kg0, hnv);
        grustep(rv, zv, inv, hnv, dv0);
#pragma unroll
        for (int rr = 0; rr < 4; ++rr) outbuf[kg * 4 + rr][90 + uA] = dv0[rr];
        // --- ug_b = w+8 (taus 18..47, wh-r resident) ---
        f32x4 rv2 = cons6<18, false>(ax, (f32x4){bsB0, bsB0, bsB0, bsB0}, ringw, toffw, pk, lane);
        rv2 = rem1(ax6, &l_wiWT[0][uB][0], zblk, kg0, rv2);
        rv2 = res6(ad, wB[3], rv2);
        rv2 = rem1(ad6, &l_whWT[0][uB][0], zblk, kg0, rv2);
        f32x4 zv2 = cons6<24, false>(ax, (f32x4){bsB1, bsB1, bsB1, bsB1}, ringw, toffw, pk, lane);
        zv2 = cons6<30, false>(ad, zv2, ringw, toffw, pk, lane);
        zv2 = rem1(ax6, &l_wiWT[1][uB][0], zblk, kg0, zv2);
        zv2 = rem1(ad6, &l_whWT[1][uB][0], zblk, kg0, zv2);
        f32x4 inv2 = cons6<36, false>(ax, (f32x4){bi2b, bi2b, bi2b, bi2b}, ringw, toffw, pk, lane);
        inv2 = rem1(ax6, &l_wiWT[2][uB][0], zblk, kg0, inv2);
        f32x4 hnv2 = cons6<42, false>(ad, (f32x4){bh2b, bh2b, bh2b, bh2b}, ringw, toffw, pk, lane);
        hnv2 = rem1(ad6, &l_whWT[2][uB][0], zblk, kg0, hnv2);
        grustep(rv2, zv2, inv2, hnv2, dv1);
        if (uB < 200) {
#pragma unroll
          for (int rr = 0; rr < 4; ++rr) outbuf[kg * 4 + rr][90 + uB] = dv1[rr];
        }
      } else {
        // --- single ug = w (taus 0..17, wh resident) ---
        f32x4 rv = cons6<0, true>(ax, (f32x4){bsA0, bsA0, bsA0, bsA0}, ringw, toffw, pk, lane);
        rv = rem1(ax6, &l_wiWT[0][uA][0], zblk, kg0, rv);
        rv = res6(ad, wB[0], rv);
        rv = rem1(ad6, &l_whWT[0][uA][0], zblk, kg0, rv);
        f32x4 zv = cons6<6, true>(ax, (f32x4){bsA1, bsA1, bsA1, bsA1}, ringw, toffw, pk, lane);
        zv = rem1(ax6, &l_wiWT[1][uA][0], zblk, kg0, zv);
        zv = res6(ad, wB[1], zv);
        zv = rem1(ad6, &l_whWT[1][uA][0], zblk, kg0, zv);
        f32x4 inv = cons6<12, true>(ax, (f32x4){bi2a, bi2a, bi2a, bi2a}, ringw, toffw, pk, lane);
        inv = rem1(ax6, &l_wiWT[2][uA][0], zblk, kg0, inv);
        f32x4 hnv = res6(ad, wB[2], (f32x4){bh2a, bh2a, bh2a, bh2a});
        hnv = rem1(ad6, &l_whWT[2][uA][0], zblk, kg0, hnv);
        grustep(rv, zv, inv, hnv, dv0);
#pragma unroll
        for (int rr = 0; rr < 4; ++rr) outbuf[kg * 4 + rr][90 + uA] = dv0[rr];
      }
    }
    LGKM0; BAR();   // B2: all reads of old dA done

    // publish new deter
    {
#pragma unroll
      for (int rr = 0; rr < 4; ++rr)
        dA[uA >> 3][kg * 4 + rr][uA & 7] = f2bf(dv0[rr]);
      if (mB) {
#pragma unroll
        for (int rr = 0; rr < 4; ++rr)
          dA[uB >> 3][kg * 4 + rr][uB & 7] = f2bf(dv1[rr]);
      }
    }
    LGKM0; BAR();   // B3: dA ready

    // ===== S4 (w>=5): o1 = elu(deter@obs1d + emb) =====
    if (w >= 5) {
      s16x8 ad4[6];
#pragma unroll
      for (int kt = 0; kt < 6; ++kt) ad4[kt] = *(const s16x8*)&dA[kt * 4 + kg][arow][0];
      s16x8 ad46 = *(const s16x8*)&dA[24 + kg][arow][0];
      const int ntb = (w - 5) * 4;
      {
        int c = (ntb + 0) * 16 + arow;
        f32x4 acc = cons6<18, true>(ad4, (f32x4){0.f, 0.f, 0.f, 0.f}, ringw, toffw, pk, lane);
        acc = rem1(ad46, &l_o1dWT[c][0], zblk, kg0, acc);
#pragma unroll
        for (int rr = 0; rr < 4; ++rr)
          xoA[c >> 3][kg * 4 + rr][c & 7] = f2bf(eluf(acc[rr] + bf2f(e16[0 * 4 + rr])));
      }
      {
        int c = (ntb + 1) * 16 + arow;
        f32x4 acc = cons6<24, true>(ad4, (f32x4){0.f, 0.f, 0.f, 0.f}, ringw, toffw, pk, lane);
        acc = rem1(ad46, &l_o1dWT[c][0], zblk, kg0, acc);
#pragma unroll
        for (int rr = 0; rr < 4; ++rr)
          xoA[c >> 3][kg * 4 + rr][c & 7] = f2bf(eluf(acc[rr] + bf2f(e16[1 * 4 + rr])));
      }
      {
        int c = (ntb + 2) * 16 + arow;
        f32x4 acc = cons6<30, true>(ad4, (f32x4){0.f, 0.f, 0.f, 0.f}, ringw, toffw, pk, lane);
        acc = rem1(ad46, &l_o1dWT[c][0], zblk, kg0, acc);
#pragma unroll
        for (int rr = 0; rr < 4; ++rr)
          xoA[c >> 3][kg * 4 + rr][c & 7] = f2bf(eluf(acc[rr] + bf2f(e16[2 * 4 + rr])));
      }
      {
        int c = (ntb + 3) * 16 + arow;
        f32x4 acc = cons6<36, true>(ad4, (f32x4){0.f, 0.f, 0.f, 0.f}, ringw, toffw, pk, lane);
        acc = rem1(ad46, &l_o1dWT[c][0], zblk, kg0, acc);
#pragma unroll
        for (int rr = 0; rr < 4; ++rr)
          xoA[c >> 3][kg * 4 + rr][c & 7] = f2bf(eluf(acc[rr] + bf2f(e16[3 * 4 + rr])));
      }
      if (w == 5) {  // nt12 resident
        int c = 192 + arow;
        f32x4 acc = res6(ad4, wB[3], (f32x4){0.f, 0.f, 0.f, 0.f});
        acc = rem1(ad46, &l_o1dWT[c][0], zblk, kg0, acc);
        if (c < 200) {
#pragma unroll
          for (int rr = 0; rr < 4; ++rr)
            xoA[c >> 3][kg * 4 + rr][c & 7] = f2bf(eluf(acc[rr] + bf2f(e16[16 + rr])));
        }
      }
    }
    LGKM0; BAR();   // B4: o1 ready

    // ===== S5 (w>=5): o = o1@obs2 + b =====
    if (w >= 5) {
      s16x8 a5[6];
#pragma unroll
      for (int kt = 0; kt < 6; ++kt) a5[kt] = *(const s16x8*)&xoA[kt * 4 + kg][arow][0];
      s16x8 a56 = *(const s16x8*)&xoA[24 + kg][arow][0];
      int c5 = (w == 5) ? arow : (w == 6) ? (16 + arow) : (48 + arow);
      f32x4 acc = cons6<42, true>(a5, (f32x4){b5a, b5a, b5a, b5a}, ringw, toffw, pk, lane);
      {
        int c5c = (c5 < 64) ? c5 : 63;
        acc = rem1(a56, &l_o2WT[c5c][0], zblk, kg0, acc);
      }
      if (c5 < 60) *(f32x4*)&s_o[c5][kg * 4] = acc;
      if (w == 7) {  // resident o2 nt2
        int c5r = 32 + arow;
        f32x4 acc2 = res6(a5, wB[3], (f32x4){b5b, b5b, b5b, b5b});
        acc2 = rem1(a56, &l_o2WT[c5r][0], zblk, kg0, acc2);
        *(f32x4*)&s_o[c5r][kg * 4] = acc2;
      }
    }
    LGKM0; BAR();   // B5: s_o ready

    // ===== S6: sampling + aux prefetch =====
    MEMCLB;
    {
      if (tid < 480) {
        int r = tid / 30, j = tid % 30;
        float qm = s_o[j][r];
        float qs = softpf(s_o[j + 30][r]) + 0.1f;
        float qst = qm + qs * epsv;
        outbuf[r][j] = qm; outbuf[r][30 + j] = qs; outbuf[r][60 + j] = qst;
        sA[j >> 3][r][j & 7] = f2bf(qst);
      }
      if (lane < 20) {
        int sl = w * 20 + lane; int kk = sl % 10, r = sl / 10;
        sA[(30 + kk) >> 3][r][(30 + kk) & 7] = f2bf(actn);
      }
      int tc = (t + 1 < T_) ? t + 1 : T_ - 1;   // consumed at t+1
      int ta = (t + 2 < T_) ? t + 2 : T_ - 1;   // action consumed at t+2's S1
      MEMCLB;
      if (w >= 5) {
#pragma unroll
        for (int i = 0; i < 5; ++i) {
          int nt = (w == 5) ? ((i < 4) ? i : 12) : ((w == 6) ? (4 + ((i < 4) ? i : 3)) : (8 + ((i < 4) ? i : 3)));
          int c = nt * 16 + arow; int cc = (c < 200) ? c : 199;
#pragma unroll
          for (int rr = 0; rr < 4; ++rr)
            e16[i * 4 + rr] = emb_pre[((size_t)tc * 1024 + b0 + kg * 4 + rr) * 200 + cc];
        }
      }
      { int it = (tid < 480) ? tid : 479;
        epsv = eps_post[((size_t)tc * 1024 + b0 + it / 30) * 30 + it % 30]; }
      { int sl = (lane < 20) ? (w * 20 + lane) : (w * 20);
        actn = action[((size_t)(b0 + sl / 10) * T_ + ta) * 10 + sl % 10]; }
      MEMCLB;
    }
    LGKM0; BAR();   // B6: outbuf/sA ready

    // ===== S7: coalesced stores =====
#pragma unroll
    for (int k2 = 0; k2 < 3; ++k2) {
      int idx = tid + k2 * 512; idx = (idx < 1168) ? idx : 1167;
      int row = idx / 73, ci = idx - row * 73;
      f32x4 v = *(const f32x4*)&outbuf[row][ci * 4];
      *(f32x4*)(out + ((size_t)(b0 + row) * T_ + t) * 580 + ci * 4) = v;
    }
    MEMCLB;
  }
}

// --------------------------------------------------------------------------
// post_head: prior head (img2->elu->img3), time-parallel; copies deter dup.
// --------------------------------------------------------------------------
__global__ __launch_bounds__(256) void post_head(const float* __restrict__ eps_prior,
                                                 const float* __restrict__ img2_b,
                                                 const float* __restrict__ img3_b,
                                                 const unsigned short* __restrict__ pk,
                                                 float* __restrict__ out) {
  __shared__ __align__(16) unsigned short dAp[4][28][16][8];
  __shared__ __align__(16) unsigned short y1p[4][28][16][8];
  __shared__ __align__(16) float s_p[60][68];
  int b = blockIdx.x;
  int tid = threadIdx.x;
  int lane = tid & 63, w = tid >> 6, arow = lane & 15, kg = lane >> 4;

  for (int i = tid; i < 1536; i += 256) {
    int mt = i / 384, rem = i % 384;
    int gidx = 25 + rem / 128, r2 = (rem % 128) / 8, j = rem & 7;
    dAp[mt][gidx][r2][j] = 0;
    y1p[mt][gidx][r2][j] = 0;
  }
  for (int i = tid; i < 12800; i += 256) {
    int row = i / 200, c = i % 200;
    float v = out[((size_t)(b * 64 + row)) * 580 + 90 + c];
    dAp[row >> 4][c >> 3][row & 15][c & 7] = f2bf(v);
  }
  __syncthreads();

  s16x8 ad[7];
#pragma unroll
  for (int kt = 0; kt < 7; ++kt) ad[kt] = *(const s16x8*)&dAp[w][kt * 4 + kg][arow][0];
#pragma unroll
  for (int nt = 0; nt < 13; ++nt) {
    int col = nt * 16 + arow;
    float bv = (col < 200) ? img2_b[col] : 0.f;
    f32x4 acc = {bv, bv, bv, bv};
#pragma unroll
    for (int kt = 0; kt < 7; ++kt) {
      s16x8 Bv = *(const s16x8*)(pk + OPI2 + (size_t)((nt * 7 + kt) * 512) + lane * 8);
      acc = __builtin_amdgcn_mfma_f32_16x16x32_bf16(ad[kt], Bv, acc, 0, 0, 0);
    }
    if (col < 200) {
#pragma unroll
      for (int rr = 0; rr < 4; ++rr)
        y1p[w][col >> 3][kg * 4 + rr][col & 7] = f2bf(eluf(acc[rr]));
    }
  }
  __syncthreads();

  s16x8 ay[7];
#pragma unroll
  for (int kt = 0; kt < 7; ++kt) ay[kt] = *(const s16x8*)&y1p[w][kt * 4 + kg][arow][0];
#pragma unroll
  for (int nt = 0; nt < 4; ++nt) {
    int col = nt * 16 + arow;
    float bv = (col < 60) ? img3_b[col] : 0.f;
    f32x4 acc = {bv, bv, bv, bv};
#pragma unroll
    for (int kt = 0; kt < 7; ++kt) {
      s16x8 Bv = *(const s16x8*)(pk + OPI3 + (size_t)((nt * 7 + kt) * 512) + lane * 8);
      acc = __builtin_amdgcn_mfma_f32_16x16x32_bf16(ay[kt], Bv, acc, 0, 0, 0);
    }
    if (col < 60) {
#pragma unroll
      for (int rr = 0; rr < 4; ++rr) s_p[col][w * 16 + kg * 4 + rr] = acc[rr];
    }
  }
  __syncthreads();

  for (int i = tid; i < 1920; i += 256) {
    int row = i / 30, j = i % 30;
    float pm = s_p[j][row];
    float ps = softpf(s_p[j + 30][row]) + 0.1f;
    float pst = pm + ps * eps_prior[((size_t)row * 1024 + b) * 30 + j];
    size_t ob = ((size_t)b * 64 + row) * 580;
    out[ob + 290 + j] = pm;
    out[ob + 320 + j] = ps;
    out[ob + 350 + j] = pst;
  }
  for (int i = tid; i < 6400; i += 256) {
    int row = i / 100, c2 = i % 100;
    size_t ob = ((size_t)b * 64 + row) * 580;
    *(float2*)&out[ob + 380 + c2 * 2] = *(const float2*)&out[ob + 90 + c2 * 2];
  }
}

extern "C" void kernel_launch(void* const* d_in, const int* in_sizes, int n_in,
                              void* d_out, int out_size, void* d_ws, size_t ws_size,
                              hipStream_t stream) {
  const float* embed    = (const float*)d_in[0];
  const float* action   = (const float*)d_in[1];
  const float* eps_post = (const float*)d_in[2];
  const float* eps_prior= (const float*)d_in[3];
  const float* img1_w   = (const float*)d_in[4];
  const float* img1_b   = (const float*)d_in[5];
  const float* gru_wi   = (const float*)d_in[6];
  const float* gru_wh   = (const float*)d_in[7];
  const float* gru_bi   = (const float*)d_in[8];
  const float* gru_bh   = (const float*)d_in[9];
  const float* img2_w   = (const float*)d_in[10];
  const float* img2_b   = (const float*)d_in[11];
  const float* img3_w   = (const float*)d_in[12];
  const float* img3_b   = (const float*)d_in[13];
  const float* obs1_w   = (const float*)d_in[14];
  const float* obs1_b   = (const float*)d_in[15];
  const float* obs2_w   = (const float*)d_in[16];
  const float* obs2_b   = (const float*)d_in[17];

  char* ws = (char*)d_ws;
  unsigned short* emb_pre = (unsigned short*)ws;
  unsigned short* pkw     = (unsigned short*)(ws + OFF_PK);
  unsigned short* swz     = (unsigned short*)(ws + OFF_SWZ);
  float* outp = (float*)d_out;

  prep_weights<<<256, 256, 0, stream>>>(img1_w, gru_wi, gru_wh, img2_w, img3_w,
                                        obs1_w, obs2_w, pkw, swz);
  emb_gemm<<<1024, 256, 0, stream>>>(embed, obs1_b, swz, emb_pre);
  scan_v7<<<64, 512, 0, stream>>>(action, eps_post, img1_b, gru_bi, gru_bh,
                                  obs2_b, pkw, emb_pre, outp);
  post_head<<<1024, 256, 0, stream>>>(eps_prior, img2_b, img3_b, pkw, outp);
}